// Round 7
// baseline (419.531 us; speedup 1.0000x reference)
//
#include <hip/hip_runtime.h>
#include <hip/hip_bf16.h>
#include <stdint.h>

typedef unsigned short u16;
typedef __attribute__((ext_vector_type(8))) short short8;
typedef __attribute__((ext_vector_type(4))) float floatx4;
typedef __attribute__((ext_vector_type(4))) unsigned int uint4_t;

#define BT 200      // B*T
#define NOBJ 30
#define KP 4224     // row stride for Sb/Wc1T/W2aTs (4097 padded, 3x22x64 for seg1)
#define DIN 4097
#define DH1 512
#define DH2 256
#define DFF 512
#define NBIGF 2112       // fold_big blocks (4224/32 x 512/32)
#define NSMALL 512
#define NSUMS (BT*17)    // S-compute blocks (17 chunks of 256 k)
#define NZERO 128

__device__ __forceinline__ u16 f2bf(float f) {
    union { float f; uint32_t u; } c; c.f = f;
    uint32_t u = c.u;
    u += 0x7FFF + ((u >> 16) & 1);
    return (u16)(u >> 16);
}

// pack 2 fp32 -> 2 bf16 in one dword (v_cvt_pk_bf16_f32 on gfx950)
__device__ __forceinline__ uint32_t pk2(float a, float b) {
    __hip_bfloat162 h = __float22bfloat162_rn(make_float2(a, b));
    uint32_t u; __builtin_memcpy(&u, &h, 4); return u;
}

// async global->LDS DMA, 16B/lane; LDS dest is wave-uniform base + lane*16
__device__ __forceinline__ void load16_lds(const u16* g, u16* l) {
    __builtin_amdgcn_global_load_lds(
        (const __attribute__((address_space(1))) void*)g,
        (__attribute__((address_space(3))) void*)l, 16, 0, 0);
}

// ======== prep_all: fold_big | fold_small | S row-sums | zero ========
__global__ void prep_all(const float* __restrict__ W1a, const float* __restrict__ W2a,
                         const float* __restrict__ W1b, const float* __restrict__ W2b,
                         const float* __restrict__ feat, const float* __restrict__ depth,
                         u16* __restrict__ Wc1T, u16* __restrict__ W2aTs,
                         u16* __restrict__ Wc2T, u16* __restrict__ W2bTs,
                         u16* __restrict__ Sb,
                         float* __restrict__ zeroBase, size_t zeroQuads) {
    __shared__ float t1[32][33];
    __shared__ float t2[32][33];
    int bid = blockIdx.x, tid = threadIdx.x;
    if (bid < NBIGF) {
        int kb = (bid % 132) * 32, jb = (bid / 132) * 32;
        int tx = tid & 31, ty = tid >> 5;   // 32 x 8
        #pragma unroll
        for (int r = 0; r < 32; r += 8) {
            int k = kb + ty + r, j = jb + tx;
            float a = 0.f, b = 0.f;
            if (k < DIN) { a = W1a[k * DH1 + j]; b = W2a[k * DH1 + j]; }
            float bs = b * (1.f / 29.f);
            t1[ty + r][tx] = a - bs;
            t2[ty + r][tx] = bs;
        }
        __syncthreads();
        #pragma unroll
        for (int r = 0; r < 32; r += 8) {
            int j = jb + ty + r, k = kb + tx;
            Wc1T[(size_t)j * KP + k]  = f2bf(t1[tx][ty + r]);
            W2aTs[(size_t)j * KP + k] = f2bf(t2[tx][ty + r]);
        }
    } else if (bid < NBIGF + NSMALL) {
        int idx = (bid - NBIGF) * 256 + tid;   // 256*512 total
        int j = idx >> 9, k = idx & 511;
        float a = W1b[k * DH2 + j];
        float b = W2b[k * DH2 + j] * (1.f / 29.f);
        Wc2T[j * DH1 + k]  = f2bf(a - b);
        W2bTs[j * DH1 + k] = f2bf(b);
    } else if (bid < NBIGF + NSMALL + NSUMS) {
        int cid = bid - NBIGF - NSMALL;
        int bt = cid / 17;
        int k = (cid % 17) * 256 + tid;
        if (k >= KP) return;
        float s = 0.f;
        if (k < 4096) {
            for (int n = 0; n < NOBJ; n++)
                s += feat[(size_t)(bt * NOBJ + n) * 4096 + k];
        } else if (k == 4096) {
            for (int n = 0; n < NOBJ; n++)
                s += depth[bt * NOBJ + n];
        }
        Sb[(size_t)bt * KP + k] = f2bf(s);
    } else {
        int zid = bid - NBIGF - NSMALL - NSUMS;
        float4* p = (float4*)zeroBase;
        float4 zz = {0.f, 0.f, 0.f, 0.f};
        for (size_t idx = (size_t)zid * 256 + tid; idx < zeroQuads; idx += (size_t)NZERO * 256)
            p[idx] = zz;
    }
}

// ======== gemmA: 128x128 bf16 MFMA, BK=64, split-K atomic ========
// seg0 (376): hacc += feat(fp32->bf16 cvt staging) @ Wc1T  (M=6000, N=512, K=4096, z=2)
// seg1 ( 24): u    += Sb @ W2aTs (DMA staging, M=200, N=512, K=4224, z=3)
__global__ __launch_bounds__(256) void gemmA(
    const float* __restrict__ feat, const u16* __restrict__ Wc1T,
    const u16* __restrict__ Sb, const u16* __restrict__ W2aTs,
    float* __restrict__ hacc, float* __restrict__ uOut) {
    __shared__ __align__(16) u16 Al[8192];   // 16 KB
    __shared__ __align__(16) u16 Bl[8192];   // 16 KB
    int bid = blockIdx.x;
    int seg0 = bid < 376;
    const u16* Bp;
    float* outF;
    int m0, n0, kbeg, kiters, M;
    if (seg0) {
        int x = bid & 3, y = (bid >> 2) % 47, z = bid / 188;
        Bp = Wc1T; outF = hacc; M = 6000;
        m0 = y * 128; n0 = x * 128; kbeg = z * 2048; kiters = 32;
    } else {
        int rem = bid - 376;
        int x = rem & 3, y = (rem >> 2) & 1, z = rem >> 3;
        Bp = W2aTs; outF = uOut; M = BT;
        m0 = y * 128; n0 = x * 128; kbeg = z * 1408; kiters = 22;
    }
    int tid = threadIdx.x, lane = tid & 63, w = tid >> 6;
    floatx4 acc[4][4] = {};
    int lrow = lane & 15, q = lane >> 4;
    int wm = (w & 1) * 64, wn = (w >> 1) * 64;
    int swz = lrow & 7;
    // staging indices
    int arow = tid >> 1, asg = tid & 1;           // seg0 A: 2 thr/row, 32 floats each
    int grow = m0 + arow; if (grow > 5999) grow = 5999;
    const float* asrc0 = feat + (size_t)grow * 4096 + asg * 32;
    u16* adst0 = Al + arow * 64 + ((asg * 4 + 0) ^ (arow & 7)) * 8;
    u16* adst1 = Al + arow * 64 + ((asg * 4 + 1) ^ (arow & 7)) * 8;
    u16* adst2 = Al + arow * 64 + ((asg * 4 + 2) ^ (arow & 7)) * 8;
    u16* adst3 = Al + arow * 64 + ((asg * 4 + 3) ^ (arow & 7)) * 8;
    int srB = tid >> 3, ksl = tid & 7;            // DMA loader lane map

    for (int i = 0; i < kiters; i++) {
        int kb = kbeg + i * 64;
        if (seg0) {
            const float4* s4 = (const float4*)(asrc0 + kb);
            float4 f0 = s4[0], f1 = s4[1], f2 = s4[2], f3 = s4[3];
            float4 f4 = s4[4], f5 = s4[5], f6 = s4[6], f7 = s4[7];
            uint4_t w0 = {pk2(f0.x,f0.y), pk2(f0.z,f0.w), pk2(f1.x,f1.y), pk2(f1.z,f1.w)};
            uint4_t w1 = {pk2(f2.x,f2.y), pk2(f2.z,f2.w), pk2(f3.x,f3.y), pk2(f3.z,f3.w)};
            uint4_t w2 = {pk2(f4.x,f4.y), pk2(f4.z,f4.w), pk2(f5.x,f5.y), pk2(f5.z,f5.w)};
            uint4_t w3 = {pk2(f6.x,f6.y), pk2(f6.z,f6.w), pk2(f7.x,f7.y), pk2(f7.z,f7.w)};
            *(uint4_t*)adst0 = w0;
            *(uint4_t*)adst1 = w1;
            *(uint4_t*)adst2 = w2;
            *(uint4_t*)adst3 = w3;
            #pragma unroll
            for (int it = 0; it < 4; it++) {
                int rowb = it * 32 + srB;
                int kph = ksl ^ (rowb & 7);
                load16_lds(Bp + (size_t)(n0 + rowb) * KP + kb + kph * 8,
                           Bl + it * 2048 + w * 512);
            }
        } else {
            #pragma unroll
            for (int it = 0; it < 4; it++) {
                int rowb = it * 32 + srB;
                int kph = ksl ^ (rowb & 7);
                load16_lds(Sb + (size_t)(m0 + rowb) * KP + kb + kph * 8,
                           Al + it * 2048 + w * 512);
                load16_lds(Bp + (size_t)(n0 + rowb) * KP + kb + kph * 8,
                           Bl + it * 2048 + w * 512);
            }
        }
        __syncthreads();
        #pragma unroll
        for (int h = 0; h < 2; h++) {
            int so = ((h * 4 + q) ^ swz) * 8;
            short8 af[4], bfv[4];
            #pragma unroll
            for (int ii = 0; ii < 4; ii++)
                af[ii] = *(short8*)(Al + (wm + ii * 16 + lrow) * 64 + so);
            #pragma unroll
            for (int j = 0; j < 4; j++)
                bfv[j] = *(short8*)(Bl + (wn + j * 16 + lrow) * 64 + so);
            #pragma unroll
            for (int ii = 0; ii < 4; ii++)
                #pragma unroll
                for (int j = 0; j < 4; j++)
                    acc[ii][j] = __builtin_amdgcn_mfma_f32_16x16x32_bf16(af[ii], bfv[j], acc[ii][j], 0, 0, 0);
        }
        __syncthreads();
    }

    #pragma unroll
    for (int ii = 0; ii < 4; ii++)
        #pragma unroll
        for (int j = 0; j < 4; j++)
            #pragma unroll
            for (int r = 0; r < 4; r++) {
                int row = m0 + wm + ii * 16 + q * 4 + r;
                int col = n0 + wn + j * 16 + lrow;
                if (row < M)
                    atomicAdd(&outF[(size_t)row * DH1 + col], acc[ii][j][r]);
            }
}

// ======== gemmB: 64x128 bf16 MFMA, BK=64, swizzled DMA, split-K atomic ========
// seg0 (376): hacc2 += hb @ Wc2T   (M=6000, z=2 x 4 iters)
// seg1 ( 16): u2    += Shb @ W2bTs (M=200,  z=2 x 4 iters)
__global__ __launch_bounds__(256) void gemmB(
    const u16* __restrict__ hb, const u16* __restrict__ Wc2T,
    const u16* __restrict__ Shb, const u16* __restrict__ W2bTs,
    float* __restrict__ hacc2, float* __restrict__ u2Out) {
    __shared__ __align__(16) u16 Al[64 * 64];    // 8 KB
    __shared__ __align__(16) u16 Bl[128 * 64];   // 16 KB
    int bid = blockIdx.x;
    const u16 *A, *B;
    float* outF;
    int m0, n0, kbeg, M;
    if (bid < 376) {
        int x = bid & 1, y = (bid >> 1) % 94, z = bid / 188;
        A = hb; B = Wc2T; outF = hacc2; M = 6000;
        m0 = y * 64; n0 = x * 128; kbeg = z * 256;
    } else {
        int rem = bid - 376;
        int x = rem & 1, y = (rem >> 1) & 3, z = rem >> 3;
        A = Shb; B = W2bTs; outF = u2Out; M = BT;
        m0 = y * 64; n0 = x * 128; kbeg = z * 256;
    }
    int kend = kbeg + 256;
    const int N = DH2, K = DH1;
    int tid = threadIdx.x;
    int lane = tid & 63, w = tid >> 6;
    int srow = tid >> 3, kslot = tid & 7;
    floatx4 acc[2][4] = {};
    int lrow = lane & 15, q = lane >> 4;
    int wm = (w & 1) * 32, wn = (w >> 1) * 64;
    int swz = lrow & 7;

    for (int kb = kbeg; kb < kend; kb += 64) {
        #pragma unroll
        for (int it = 0; it < 2; it++) {
            int row = it * 32 + srow;
            int kph = kslot ^ (row & 7);
            load16_lds(A + (size_t)(m0 + row) * K + kb + kph * 8,
                       Al + it * 2048 + w * 512);
        }
        #pragma unroll
        for (int it = 0; it < 4; it++) {
            int row = it * 32 + srow;
            int kph = kslot ^ (row & 7);
            load16_lds(B + (size_t)(n0 + row) * K + kb + kph * 8,
                       Bl + it * 2048 + w * 512);
        }
        __syncthreads();
        #pragma unroll
        for (int h = 0; h < 2; h++) {
            int so = ((h * 4 + q) ^ swz) * 8;
            short8 af[2], bfv[4];
            #pragma unroll
            for (int i = 0; i < 2; i++)
                af[i] = *(short8*)(Al + (wm + i * 16 + lrow) * 64 + so);
            #pragma unroll
            for (int j = 0; j < 4; j++)
                bfv[j] = *(short8*)(Bl + (wn + j * 16 + lrow) * 64 + so);
            #pragma unroll
            for (int i = 0; i < 2; i++)
                #pragma unroll
                for (int j = 0; j < 4; j++)
                    acc[i][j] = __builtin_amdgcn_mfma_f32_16x16x32_bf16(af[i], bfv[j], acc[i][j], 0, 0, 0);
        }
        __syncthreads();
    }

    #pragma unroll
    for (int i = 0; i < 2; i++)
        #pragma unroll
        for (int j = 0; j < 4; j++)
            #pragma unroll
            for (int r = 0; r < 4; r++) {
                int row = m0 + wm + i * 16 + q * 4 + r;
                int col = n0 + wn + j * 16 + lrow;
                if (row < M)
                    atomicAdd(&outF[(size_t)row * N + col], acc[i][j][r]);
            }
}

// -------- reduce1: h = relu(hacc + u + b1a + depth*wr) -> bf16 hb; node-sum -> Shb --------
__global__ void reduce1(const float* __restrict__ hacc, const float* __restrict__ u,
                        const float* __restrict__ b1a,
                        const float* __restrict__ depth,
                        const float* __restrict__ W1a, const float* __restrict__ W2a,
                        u16* __restrict__ hb, u16* __restrict__ Shb) {
    __shared__ float sl[128];
    __shared__ float dl[NOBJ];
    int bt = blockIdx.x, c0 = blockIdx.y * 128;
    int lc = threadIdx.x & 127, rp = threadIdx.x >> 7;
    int col = c0 + lc;
    if (threadIdx.x < NOBJ) dl[threadIdx.x] = depth[bt * NOBJ + threadIdx.x];
    float ub = u[bt * DH1 + col] + b1a[col];
    // rank-1 depth term: Wc1[4096, col] = W1a[4096,col] - W2a[4096,col]/29
    float wr = W1a[(size_t)4096 * DH1 + col] - W2a[(size_t)4096 * DH1 + col] * (1.f / 29.f);
    __syncthreads();
    float s = 0.f;
    for (int n = rp; n < NOBJ; n += 2) {
        float v = hacc[(size_t)(bt * NOBJ + n) * DH1 + col] + ub + dl[n] * wr;
        v = v > 0.f ? v : 0.f;
        hb[(size_t)(bt * NOBJ + n) * DH1 + col] = f2bf(v);
        s += v;
    }
    if (rp == 0) sl[lc] = s;
    __syncthreads();
    if (rp == 1) Shb[bt * DH1 + col] = f2bf(sl[lc] + s);
}

// -------- reduce2_qkv: g = mean_n relu(hacc2 + u2 + b1b); q,k,v = g @ W --------
__global__ void reduce2_qkv(const float* __restrict__ hacc2, const float* __restrict__ u2,
                            const float* __restrict__ b1b,
                            const float* __restrict__ Wq, const float* __restrict__ Wk,
                            const float* __restrict__ Wv,
                            float* __restrict__ g, float* __restrict__ q,
                            float* __restrict__ k, float* __restrict__ v) {
    __shared__ float gl[DH2];
    int bt = blockIdx.x, j = threadIdx.x;
    float ub = u2[bt * DH2 + j] + b1b[j];
    float a = 0.f;
    for (int n = 0; n < NOBJ; n++) {
        float vv = hacc2[(size_t)(bt * NOBJ + n) * DH2 + j] + ub;
        a += vv > 0.f ? vv : 0.f;
    }
    a *= (1.f / 30.f);
    gl[j] = a;
    g[bt * DH2 + j] = a;
    __syncthreads();
    float aq = 0.f, ak = 0.f, av = 0.f;
    for (int kk = 0; kk < DH2; kk++) {
        float x = gl[kk];
        aq += x * Wq[kk * DH2 + j];
        ak += x * Wk[kk * DH2 + j];
        av += x * Wv[kk * DH2 + j];
    }
    q[bt * DH2 + j] = aq;
    k[bt * DH2 + j] = ak;
    v[bt * DH2 + j] = av;
}

// -------- fused attention + Wo + LN1 + FFN + LN2 + classifier --------
__device__ __forceinline__ float block_sum256(float v, volatile float* red) {
    #pragma unroll
    for (int o = 32; o > 0; o >>= 1) v += __shfl_down(v, o);
    int w = threadIdx.x >> 6;
    __syncthreads();
    if ((threadIdx.x & 63) == 0) red[w] = v;
    __syncthreads();
    return red[0] + red[1] + red[2] + red[3];
}

__global__ void attn_head(const float* __restrict__ qg, const float* __restrict__ kg,
                          const float* __restrict__ vg, const float* __restrict__ g,
                          const float* __restrict__ Wo,
                          const float* __restrict__ ln1g, const float* __restrict__ ln1b,
                          const float* __restrict__ Wf1, const float* __restrict__ bf1,
                          const float* __restrict__ Wf2, const float* __restrict__ bf2,
                          const float* __restrict__ ln2g, const float* __restrict__ ln2b,
                          const float* __restrict__ Wc, const float* __restrict__ bc,
                          float* __restrict__ out) {
    __shared__ float ql[DH2];
    __shared__ float scl[4][128];
    __shared__ float ctxl[DH2];
    __shared__ float yl[DH2];
    __shared__ float ffl[DFF];
    __shared__ float red[4];
    int row = blockIdx.x, tid = threadIdx.x;
    int base = (row >= 100) ? 100 : 0;
    ql[tid] = qg[row * DH2 + tid];
    __syncthreads();

    for (int p = tid; p < 512; p += 256) {
        int h = p >> 7, s = p & 127;
        if (s < 100) {
            const float* kr = kg + (size_t)(base + s) * DH2 + h * 64;
            float a = 0.f;
            #pragma unroll 8
            for (int d = 0; d < 64; d++) a += ql[h * 64 + d] * kr[d];
            scl[h][s] = a * 0.125f;
        }
    }
    __syncthreads();

    {
        int w = tid >> 6, lane = tid & 63;
        int s2 = 64 + lane;
        float a  = scl[w][lane];
        float b2 = (s2 < 100) ? scl[w][s2] : -1e30f;
        float m = fmaxf(a, b2);
        #pragma unroll
        for (int o = 32; o > 0; o >>= 1) m = fmaxf(m, __shfl_down(m, o));
        m = __shfl(m, 0);
        float e1 = __expf(a - m);
        float e2 = (s2 < 100) ? __expf(b2 - m) : 0.f;
        float sm = e1 + e2;
        #pragma unroll
        for (int o = 32; o > 0; o >>= 1) sm += __shfl_down(sm, o);
        sm = __shfl(sm, 0);
        float r = 1.f / sm;
        scl[w][lane] = e1 * r;
        if (s2 < 100) scl[w][s2] = e2 * r;
    }
    __syncthreads();

    {
        int h = tid >> 6;
        float o = 0.f;
        for (int s = 0; s < 100; s++)
            o += scl[h][s] * vg[(size_t)(base + s) * DH2 + tid];
        ctxl[tid] = o;
    }
    __syncthreads();

    float o = 0.f;
    for (int kk = 0; kk < DH2; kk++) o += ctxl[kk] * Wo[kk * DH2 + tid];
    float t = g[row * DH2 + tid] + o;
    float mu  = block_sum256(t, red) * (1.f / DH2);
    float ex2 = block_sum256(t * t, red) * (1.f / DH2);
    float y = (t - mu) * rsqrtf(ex2 - mu * mu + 1e-5f) * ln1g[tid] + ln1b[tid];
    yl[tid] = y;
    __syncthreads();
    for (int jj = tid; jj < DFF; jj += 256) {
        float a = bf1[jj];
        for (int kk = 0; kk < DH2; kk++) a += yl[kk] * Wf1[kk * DFF + jj];
        ffl[jj] = a > 0.f ? a : 0.f;
    }
    __syncthreads();
    float o2 = bf2[tid];
    for (int kk = 0; kk < DFF; kk++) o2 += ffl[kk] * Wf2[kk * DH2 + tid];
    float z0 = y + o2;
    float mu2  = block_sum256(z0, red) * (1.f / DH2);
    float ex22 = block_sum256(z0 * z0, red) * (1.f / DH2);
    float z = (z0 - mu2) * rsqrtf(ex22 - mu2 * mu2 + 1e-5f) * ln2g[tid] + ln2b[tid];
    float logit = block_sum256(z * Wc[tid], red) + bc[0];
    if (tid == 0) {
        out[row]      = 1.f / (1.f + __expf(-logit));
        out[BT + row] = 0.f;
    }
}

// ---------------- launch ----------------
extern "C" void kernel_launch(void* const* d_in, const int* in_sizes, int n_in,
                              void* d_out, int out_size, void* d_ws, size_t ws_size,
                              hipStream_t stream) {
    const float* feat  = (const float*)d_in[0];
    const float* depth = (const float*)d_in[1];
    const float* W1a = (const float*)d_in[2];
    const float* W2a = (const float*)d_in[3];
    const float* b1a = (const float*)d_in[4];
    const float* W1b = (const float*)d_in[5];
    const float* W2b = (const float*)d_in[6];
    const float* b1b = (const float*)d_in[7];
    const float* Wq  = (const float*)d_in[8];
    const float* Wk  = (const float*)d_in[9];
    const float* Wv  = (const float*)d_in[10];
    const float* Wo  = (const float*)d_in[11];
    const float* ln1g = (const float*)d_in[12];
    const float* ln1b = (const float*)d_in[13];
    const float* Wf1 = (const float*)d_in[14];
    const float* bf1 = (const float*)d_in[15];
    const float* Wf2 = (const float*)d_in[16];
    const float* bf2 = (const float*)d_in[17];
    const float* ln2g = (const float*)d_in[18];
    const float* ln2b = (const float*)d_in[19];
    const float* Wc  = (const float*)d_in[20];
    const float* bc  = (const float*)d_in[21];
    float* out = (float*)d_out;
    char* ws = (char*)d_ws;

    size_t off = 0;
    u16* Sb    = (u16*)(ws + off); off += (size_t)256 * KP * 2;      // 2.2 MB
    u16* Wc1T  = (u16*)(ws + off); off += (size_t)DH1 * KP * 2;      // 4.3 MB
    u16* W2aTs = (u16*)(ws + off); off += (size_t)DH1 * KP * 2;
    u16* Wc2T  = (u16*)(ws + off); off += (size_t)DH2 * DH1 * 2;
    u16* W2bTs = (u16*)(ws + off); off += (size_t)DH2 * DH1 * 2;
    u16* hb    = (u16*)(ws + off); off += (size_t)6016 * DH1 * 2;    // 6.2 MB
    u16* Shb   = (u16*)(ws + off); off += (size_t)256 * DH1 * 2;
    // contiguous zero region (cleared by prep_all)
    char* zBase = ws + off;
    float* hacc  = (float*)(ws + off); off += (size_t)6000 * DH1 * 4;  // 12.3 MB
    float* hacc2 = (float*)(ws + off); off += (size_t)6000 * DH2 * 4;  //  6.1 MB
    float* u     = (float*)(ws + off); off += (size_t)BT * DH1 * 4;
    float* u2    = (float*)(ws + off); off += (size_t)BT * DH2 * 4;
    size_t zeroQuads = (size_t)(ws + off - zBase) / 16;
    float* g = (float*)(ws + off); off += (size_t)BT * DH2 * 4;
    float* q = (float*)(ws + off); off += (size_t)BT * DH2 * 4;
    float* k = (float*)(ws + off); off += (size_t)BT * DH2 * 4;
    float* v = (float*)(ws + off); off += (size_t)BT * DH2 * 4;

    prep_all<<<NBIGF + NSMALL + NSUMS + NZERO, 256, 0, stream>>>(
        W1a, W2a, W1b, W2b, feat, depth,
        Wc1T, W2aTs, Wc2T, W2bTs, Sb, (float*)zBase, zeroQuads);
    // hacc += feat@Wc1T (376 blocks, z=2, K=4096) ; u += Sb@W2aTs (24 blocks, z=3, K=4224)
    gemmA<<<376 + 24, 256, 0, stream>>>(feat, Wc1T, Sb, W2aTs, hacc, u);
    reduce1<<<dim3(BT, 4), 256, 0, stream>>>(hacc, u, b1a, depth, W1a, W2a, hb, Shb);
    // hacc2 += hb@Wc2T (376 blocks, z=2) ; u2 += Shb@W2bTs (16 blocks, z=2)
    gemmB<<<376 + 16, 256, 0, stream>>>(hb, Wc2T, Shb, W2bTs, hacc2, u2);
    reduce2_qkv<<<BT, DH2, 0, stream>>>(hacc2, u2, b1b, Wq, Wk, Wv, g, q, k, v);
    attn_head<<<BT, DH2, 0, stream>>>(q, k, v, g, Wo, ln1g, ln1b, Wf1, bf1,
                                      Wf2, bf2, ln2g, ln2b, Wc, bc, out);
}

// Round 8
// 393.155 us; speedup vs baseline: 1.0671x; 1.0671x over previous
//
#include <hip/hip_runtime.h>
#include <hip/hip_bf16.h>
#include <stdint.h>

typedef unsigned short u16;
typedef __attribute__((ext_vector_type(8))) short short8;
typedef __attribute__((ext_vector_type(4))) float floatx4;

#define BT 200      // B*T
#define NOBJ 30
#define KP2 4224    // padded K: 3 z-slices x 22 iters x 64
#define DIN 4097
#define DH1 512
#define DH2 256
#define DFF 512
#define MPAD 6016
#define CHZ 176     // k-chunks (of 8) per z-slice
#define NBIGW (132*16)   // fold_big blocks
#define NSMALL 512
#define NCONV (BT*12)    // conv blocks: 3 chunk-parts x 4 n-slices per bt
#define NZERO 128

__device__ __forceinline__ u16 f2bf(float f) {
    union { float f; uint32_t u; } c; c.f = f;
    uint32_t u = c.u;
    u += 0x7FFF + ((u >> 16) & 1);
    return (u16)(u >> 16);
}

// async global->LDS DMA, 16B/lane; LDS dest is wave-uniform base + lane*16
__device__ __forceinline__ void load16_lds(const u16* g, u16* l) {
    __builtin_amdgcn_global_load_lds(
        (const __attribute__((address_space(1))) void*)g,
        (__attribute__((address_space(3))) void*)l, 16, 0, 0);
}

// tiled offset: tiles of 128 rows x (3 z x 22 iters x 64 k), storage
// [tile = y*3+z][i][row][slot]*8 ; slot = kw ^ (row&7)  (pre-swizzled)
__device__ __forceinline__ size_t tile_off(int ytile, int row, int c8) {
    int z = c8 / CHZ, rem = c8 - z * CHZ;
    int i = rem >> 3, kw = rem & 7;
    int ks = kw ^ (row & 7);
    return ((((size_t)(ytile * 3 + z) * 22 + i) * 128 + row) * 64) + ks * 8;
}

// ======== prep_all: fold_big | fold_small | conv (4-way n-split) | zero ========
__global__ void prep_all(const float* __restrict__ W1a, const float* __restrict__ W2a,
                         const float* __restrict__ W1b, const float* __restrict__ W2b,
                         const float* __restrict__ feat, const float* __restrict__ depth,
                         u16* __restrict__ Wc1T, u16* __restrict__ W2aTs,
                         u16* __restrict__ Wc2T, u16* __restrict__ W2bTs,
                         u16* __restrict__ XbT, u16* __restrict__ SbT,
                         float* __restrict__ zeroBase, size_t zeroQuads) {
    __shared__ float t1[32][33];
    __shared__ float t2[32][33];
    int bid = blockIdx.x, tid = threadIdx.x;
    if (bid < NBIGW) {
        int kb = (bid % 132) * 32, jb = (bid / 132) * 32;
        int tx = tid & 31, ty = tid >> 5;   // 32 x 8
        #pragma unroll
        for (int r = 0; r < 32; r += 8) {
            int k = kb + ty + r, j = jb + tx;
            float a = 0.f, b = 0.f;
            if (k < DIN) { a = W1a[k * DH1 + j]; b = W2a[k * DH1 + j]; }
            float bs = b * (1.f / 29.f);
            t1[ty + r][tx] = a - bs;
            t2[ty + r][tx] = bs;
        }
        __syncthreads();
        #pragma unroll
        for (int r = 0; r < 32; r += 8) {
            int j = jb + ty + r, k = kb + tx;
            int x = j >> 7, row = j & 127;
            size_t off = tile_off(x, row, k >> 3) + (k & 7);
            Wc1T[off]  = f2bf(t1[tx][ty + r]);
            W2aTs[off] = f2bf(t2[tx][ty + r]);
        }
    } else if (bid < NBIGW + NSMALL) {
        int idx = (bid - NBIGW) * 256 + tid;   // 256*512 total
        int j = idx >> 9, k = idx & 511;
        float a = W1b[k * DH2 + j];
        float b = W2b[k * DH2 + j] * (1.f / 29.f);
        Wc2T[j * DH1 + k]  = f2bf(a - b);
        W2bTs[j * DH1 + k] = f2bf(b);
    } else if (bid < NBIGW + NSMALL + NCONV) {
        int cid = bid - NBIGW - NSMALL;
        int slice = cid & 3, part = (cid >> 2) % 3, bt = cid / 12;
        int c8 = part * 256 + tid;
        if (c8 >= 528) return;
        const int nsA[4] = {0, 8, 16, 23};
        const int neA[4] = {8, 16, 23, 30};
        int k8 = c8 * 8;
        float s[8] = {};
        for (int n = nsA[slice]; n < neA[slice]; n++) {
            int r = bt * NOBJ + n;
            float v[8];
            if (k8 + 7 < 4096) {
                float4 a = *(const float4*)(feat + (size_t)r * 4096 + k8);
                float4 b = *(const float4*)(feat + (size_t)r * 4096 + k8 + 4);
                v[0]=a.x; v[1]=a.y; v[2]=a.z; v[3]=a.w;
                v[4]=b.x; v[5]=b.y; v[6]=b.z; v[7]=b.w;
            } else {
                #pragma unroll
                for (int e = 0; e < 8; e++) v[e] = 0.f;
                if (k8 == 4096) v[0] = depth[r];
            }
            short8 o;
            #pragma unroll
            for (int e = 0; e < 8; e++) { s[e] += v[e]; o[e] = (short)f2bf(v[e]); }
            *(short8*)(XbT + tile_off(r >> 7, r & 127, c8)) = o;
        }
        short8 so;
        #pragma unroll
        for (int e = 0; e < 8; e++) so[e] = (short)f2bf(s[e]);
        int grow = slice * 256 + bt;    // partial-S row (4 slices of 256)
        *(short8*)(SbT + tile_off(grow >> 7, grow & 127, c8)) = so;
    } else {
        int zid = bid - NBIGW - NSMALL - NCONV;
        float4* p = (float4*)zeroBase;
        float4 zz = {0.f, 0.f, 0.f, 0.f};
        for (size_t idx = (size_t)zid * 256 + tid; idx < zeroQuads; idx += (size_t)NZERO * 256)
            p[idx] = zz;
    }
}

// ======== gemmA: 128x128 bf16 MFMA, contiguous tiled streams, split-K atomic ========
// seg0 (564): hacc += XbT @ Wc1T   (M=6000, N=512, z=3)
// seg1 ( 96): u    += SbT @ W2aTs  (4 partial slices, out row&255, z=3)
__global__ __launch_bounds__(256) void gemmA(
    const u16* __restrict__ XbT, const u16* __restrict__ WaT,
    const u16* __restrict__ SbT, const u16* __restrict__ WsT,
    float* __restrict__ hacc, float* __restrict__ uOut) {
    __shared__ __align__(16) u16 Al[8192];   // 16 KB
    __shared__ __align__(16) u16 Bl[8192];   // 16 KB
    int bid = blockIdx.x;
    const u16 *Abase, *Bbase;
    float* outF;
    int m0, n0, seg0 = bid < 564;
    if (seg0) {
        int x = bid & 3, y = (bid >> 2) % 47, z = bid / 188;
        Abase = XbT + (size_t)((y * 3 + z) * 22) * 8192;
        Bbase = WaT + (size_t)((x * 3 + z) * 22) * 8192;
        outF = hacc; m0 = y * 128; n0 = x * 128;
    } else {
        int rem = bid - 564;
        int x = rem & 3, y = (rem >> 2) & 7, z = rem >> 5;
        Abase = SbT + (size_t)((y * 3 + z) * 22) * 8192;
        Bbase = WsT + (size_t)((x * 3 + z) * 22) * 8192;
        outF = uOut; m0 = y * 128; n0 = x * 128;
    }
    int tid = threadIdx.x, lane = tid & 63, w = tid >> 6;
    floatx4 acc[4][4] = {};
    int lrow = lane & 15, q = lane >> 4;
    int wm = (w & 1) * 64, wn = (w >> 1) * 64;
    int swz = lrow & 7;

    for (int i = 0; i < 22; i++) {
        const u16* as = Abase + (size_t)i * 8192;
        const u16* bs = Bbase + (size_t)i * 8192;
        #pragma unroll
        for (int it = 0; it < 4; it++) {
            load16_lds(as + (it * 256 + tid) * 8, Al + it * 2048 + w * 512);
            load16_lds(bs + (it * 256 + tid) * 8, Bl + it * 2048 + w * 512);
        }
        __syncthreads();
        #pragma unroll
        for (int h = 0; h < 2; h++) {
            int so = ((h * 4 + q) ^ swz) * 8;
            short8 af[4], bfv[4];
            #pragma unroll
            for (int ii = 0; ii < 4; ii++)
                af[ii] = *(short8*)(Al + (wm + ii * 16 + lrow) * 64 + so);
            #pragma unroll
            for (int j = 0; j < 4; j++)
                bfv[j] = *(short8*)(Bl + (wn + j * 16 + lrow) * 64 + so);
            #pragma unroll
            for (int ii = 0; ii < 4; ii++)
                #pragma unroll
                for (int j = 0; j < 4; j++)
                    acc[ii][j] = __builtin_amdgcn_mfma_f32_16x16x32_bf16(af[ii], bfv[j], acc[ii][j], 0, 0, 0);
        }
        __syncthreads();
    }

    #pragma unroll
    for (int ii = 0; ii < 4; ii++)
        #pragma unroll
        for (int j = 0; j < 4; j++)
            #pragma unroll
            for (int r = 0; r < 4; r++) {
                int row = m0 + wm + ii * 16 + q * 4 + r;
                int col = n0 + wn + j * 16 + lrow;
                if (seg0) {
                    if (row < 6000)
                        atomicAdd(&outF[(size_t)row * DH1 + col], acc[ii][j][r]);
                } else {
                    int urow = row & 255;   // fold 4 partial slices into u[0..199]
                    if (urow < BT)
                        atomicAdd(&outF[(size_t)urow * DH1 + col], acc[ii][j][r]);
                }
            }
}

// ======== gemmB: 64x128 bf16 MFMA, BK=64, swizzle DMA, split-K z=4 atomic ========
// seg0 (752): hacc2 += hb @ Wc2T   (M=6000, z=4 x 2 iters)
// seg1 ( 32): u2    += Shb @ W2bTs (M=200,  z=4 x 2 iters)
__global__ __launch_bounds__(256) void gemmB(
    const u16* __restrict__ hb, const u16* __restrict__ Wc2T,
    const u16* __restrict__ Shb, const u16* __restrict__ W2bTs,
    float* __restrict__ hacc2, float* __restrict__ u2Out) {
    __shared__ __align__(16) u16 Al[64 * 64];    // 8 KB
    __shared__ __align__(16) u16 Bl[128 * 64];   // 16 KB
    int bid = blockIdx.x;
    const u16 *A, *B;
    float* outF;
    int m0, n0, kbeg, M;
    if (bid < 752) {
        int x = bid & 1, y = (bid >> 1) % 94, z = bid / 188;
        A = hb; B = Wc2T; outF = hacc2; M = 6000;
        m0 = y * 64; n0 = x * 128; kbeg = z * 128;
    } else {
        int rem = bid - 752;
        int x = rem & 1, y = (rem >> 1) & 3, z = rem >> 3;
        A = Shb; B = W2bTs; outF = u2Out; M = BT;
        m0 = y * 64; n0 = x * 128; kbeg = z * 128;
    }
    int kend = kbeg + 128;
    const int N = DH2, K = DH1;
    int tid = threadIdx.x;
    int lane = tid & 63, w = tid >> 6;
    int srow = tid >> 3, kslot = tid & 7;
    floatx4 acc[2][4] = {};
    int lrow = lane & 15, q = lane >> 4;
    int wm = (w & 1) * 32, wn = (w >> 1) * 64;
    int swz = lrow & 7;

    for (int kb = kbeg; kb < kend; kb += 64) {
        #pragma unroll
        for (int it = 0; it < 2; it++) {
            int row = it * 32 + srow;
            int kph = kslot ^ (row & 7);
            load16_lds(A + (size_t)(m0 + row) * K + kb + kph * 8,
                       Al + it * 2048 + w * 512);
        }
        #pragma unroll
        for (int it = 0; it < 4; it++) {
            int row = it * 32 + srow;
            int kph = kslot ^ (row & 7);
            load16_lds(B + (size_t)(n0 + row) * K + kb + kph * 8,
                       Bl + it * 2048 + w * 512);
        }
        __syncthreads();
        #pragma unroll
        for (int h = 0; h < 2; h++) {
            int so = ((h * 4 + q) ^ swz) * 8;
            short8 af[2], bfv[4];
            #pragma unroll
            for (int i = 0; i < 2; i++)
                af[i] = *(short8*)(Al + (wm + i * 16 + lrow) * 64 + so);
            #pragma unroll
            for (int j = 0; j < 4; j++)
                bfv[j] = *(short8*)(Bl + (wn + j * 16 + lrow) * 64 + so);
            #pragma unroll
            for (int i = 0; i < 2; i++)
                #pragma unroll
                for (int j = 0; j < 4; j++)
                    acc[i][j] = __builtin_amdgcn_mfma_f32_16x16x32_bf16(af[i], bfv[j], acc[i][j], 0, 0, 0);
        }
        __syncthreads();
    }

    #pragma unroll
    for (int i = 0; i < 2; i++)
        #pragma unroll
        for (int j = 0; j < 4; j++)
            #pragma unroll
            for (int r = 0; r < 4; r++) {
                int row = m0 + wm + i * 16 + q * 4 + r;
                int col = n0 + wn + j * 16 + lrow;
                if (row < M)
                    atomicAdd(&outF[(size_t)row * N + col], acc[i][j][r]);
            }
}

// -------- reduce1: h = relu(hacc + u + b1a) -> bf16 hb; node-sum -> Shb --------
__global__ void reduce1(const float* __restrict__ hacc, const float* __restrict__ u,
                        const float* __restrict__ b1a,
                        u16* __restrict__ hb, u16* __restrict__ Shb) {
    __shared__ float sl[128];
    int bt = blockIdx.x, c0 = blockIdx.y * 128;
    int lc = threadIdx.x & 127, rp = threadIdx.x >> 7;
    int col = c0 + lc;
    float ub = u[bt * DH1 + col] + b1a[col];
    float s = 0.f;
    for (int n = rp; n < NOBJ; n += 2) {
        float v = hacc[(size_t)(bt * NOBJ + n) * DH1 + col] + ub;
        v = v > 0.f ? v : 0.f;
        hb[(size_t)(bt * NOBJ + n) * DH1 + col] = f2bf(v);
        s += v;
    }
    if (rp == 0) sl[lc] = s;
    __syncthreads();
    if (rp == 1) Shb[bt * DH1 + col] = f2bf(sl[lc] + s);
}

// -------- reduce2_qkv: g = mean_n relu(hacc2 + u2 + b1b); q,k,v = g @ W --------
__global__ void reduce2_qkv(const float* __restrict__ hacc2, const float* __restrict__ u2,
                            const float* __restrict__ b1b,
                            const float* __restrict__ Wq, const float* __restrict__ Wk,
                            const float* __restrict__ Wv,
                            float* __restrict__ g, float* __restrict__ q,
                            float* __restrict__ k, float* __restrict__ v) {
    __shared__ float gl[DH2];
    int bt = blockIdx.x, j = threadIdx.x;
    float ub = u2[bt * DH2 + j] + b1b[j];
    float a = 0.f;
    for (int n = 0; n < NOBJ; n++) {
        float vv = hacc2[(size_t)(bt * NOBJ + n) * DH2 + j] + ub;
        a += vv > 0.f ? vv : 0.f;
    }
    a *= (1.f / 30.f);
    gl[j] = a;
    g[bt * DH2 + j] = a;
    __syncthreads();
    float aq = 0.f, ak = 0.f, av = 0.f;
    for (int kk = 0; kk < DH2; kk++) {
        float x = gl[kk];
        aq += x * Wq[kk * DH2 + j];
        ak += x * Wk[kk * DH2 + j];
        av += x * Wv[kk * DH2 + j];
    }
    q[bt * DH2 + j] = aq;
    k[bt * DH2 + j] = ak;
    v[bt * DH2 + j] = av;
}

// -------- fused attention + Wo + LN1 + FFN + LN2 + classifier --------
__device__ __forceinline__ float block_sum256(float v, volatile float* red) {
    #pragma unroll
    for (int o = 32; o > 0; o >>= 1) v += __shfl_down(v, o);
    int w = threadIdx.x >> 6;
    __syncthreads();
    if ((threadIdx.x & 63) == 0) red[w] = v;
    __syncthreads();
    return red[0] + red[1] + red[2] + red[3];
}

__global__ void attn_head(const float* __restrict__ qg, const float* __restrict__ kg,
                          const float* __restrict__ vg, const float* __restrict__ g,
                          const float* __restrict__ Wo,
                          const float* __restrict__ ln1g, const float* __restrict__ ln1b,
                          const float* __restrict__ Wf1, const float* __restrict__ bf1,
                          const float* __restrict__ Wf2, const float* __restrict__ bf2,
                          const float* __restrict__ ln2g, const float* __restrict__ ln2b,
                          const float* __restrict__ Wc, const float* __restrict__ bc,
                          float* __restrict__ out) {
    __shared__ float ql[DH2];
    __shared__ float scl[4][128];
    __shared__ float ctxl[DH2];
    __shared__ float yl[DH2];
    __shared__ float ffl[DFF];
    __shared__ float red[4];
    int row = blockIdx.x, tid = threadIdx.x;
    int base = (row >= 100) ? 100 : 0;
    ql[tid] = qg[row * DH2 + tid];
    __syncthreads();

    for (int p = tid; p < 512; p += 256) {
        int h = p >> 7, s = p & 127;
        if (s < 100) {
            const float* kr = kg + (size_t)(base + s) * DH2 + h * 64;
            float a = 0.f;
            #pragma unroll 8
            for (int d = 0; d < 64; d++) a += ql[h * 64 + d] * kr[d];
            scl[h][s] = a * 0.125f;
        }
    }
    __syncthreads();

    {
        int w = tid >> 6, lane = tid & 63;
        int s2 = 64 + lane;
        float a  = scl[w][lane];
        float b2 = (s2 < 100) ? scl[w][s2] : -1e30f;
        float m = fmaxf(a, b2);
        #pragma unroll
        for (int o = 32; o > 0; o >>= 1) m = fmaxf(m, __shfl_down(m, o));
        m = __shfl(m, 0);
        float e1 = __expf(a - m);
        float e2 = (s2 < 100) ? __expf(b2 - m) : 0.f;
        float sm = e1 + e2;
        #pragma unroll
        for (int o = 32; o > 0; o >>= 1) sm += __shfl_down(sm, o);
        sm = __shfl(sm, 0);
        float r = 1.f / sm;
        scl[w][lane] = e1 * r;
        if (s2 < 100) scl[w][s2] = e2 * r;
    }
    __syncthreads();

    {
        int h = tid >> 6;
        float o = 0.f;
        for (int s = 0; s < 100; s++)
            o += scl[h][s] * vg[(size_t)(base + s) * DH2 + tid];
        ctxl[tid] = o;
    }
    __syncthreads();

    float o = 0.f;
    for (int kk = 0; kk < DH2; kk++) o += ctxl[kk] * Wo[kk * DH2 + tid];
    float t = g[row * DH2 + tid] + o;
    float mu  = block_sum256(t, red) * (1.f / DH2);
    float ex2 = block_sum256(t * t, red) * (1.f / DH2);
    float y = (t - mu) * rsqrtf(ex2 - mu * mu + 1e-5f) * ln1g[tid] + ln1b[tid];
    yl[tid] = y;
    __syncthreads();
    for (int jj = tid; jj < DFF; jj += 256) {
        float a = bf1[jj];
        for (int kk = 0; kk < DH2; kk++) a += yl[kk] * Wf1[kk * DFF + jj];
        ffl[jj] = a > 0.f ? a : 0.f;
    }
    __syncthreads();
    float o2 = bf2[tid];
    for (int kk = 0; kk < DFF; kk++) o2 += ffl[kk] * Wf2[kk * DH2 + tid];
    float z0 = y + o2;
    float mu2  = block_sum256(z0, red) * (1.f / DH2);
    float ex22 = block_sum256(z0 * z0, red) * (1.f / DH2);
    float z = (z0 - mu2) * rsqrtf(ex22 - mu2 * mu2 + 1e-5f) * ln2g[tid] + ln2b[tid];
    float logit = block_sum256(z * Wc[tid], red) + bc[0];
    if (tid == 0) {
        out[row]      = 1.f / (1.f + __expf(-logit));
        out[BT + row] = 0.f;
    }
}

// ---------------- launch ----------------
extern "C" void kernel_launch(void* const* d_in, const int* in_sizes, int n_in,
                              void* d_out, int out_size, void* d_ws, size_t ws_size,
                              hipStream_t stream) {
    const float* feat  = (const float*)d_in[0];
    const float* depth = (const float*)d_in[1];
    const float* W1a = (const float*)d_in[2];
    const float* W2a = (const float*)d_in[3];
    const float* b1a = (const float*)d_in[4];
    const float* W1b = (const float*)d_in[5];
    const float* W2b = (const float*)d_in[6];
    const float* b1b = (const float*)d_in[7];
    const float* Wq  = (const float*)d_in[8];
    const float* Wk  = (const float*)d_in[9];
    const float* Wv  = (const float*)d_in[10];
    const float* Wo  = (const float*)d_in[11];
    const float* ln1g = (const float*)d_in[12];
    const float* ln1b = (const float*)d_in[13];
    const float* Wf1 = (const float*)d_in[14];
    const float* bf1 = (const float*)d_in[15];
    const float* Wf2 = (const float*)d_in[16];
    const float* bf2 = (const float*)d_in[17];
    const float* ln2g = (const float*)d_in[18];
    const float* ln2b = (const float*)d_in[19];
    const float* Wc  = (const float*)d_in[20];
    const float* bc  = (const float*)d_in[21];
    float* out = (float*)d_out;
    char* ws = (char*)d_ws;

    size_t off = 0;
    u16* XbT   = (u16*)(ws + off); off += (size_t)MPAD * KP2 * 2;    // 50.8 MB
    u16* SbT   = (u16*)(ws + off); off += (size_t)1024 * KP2 * 2;    //  8.65 MB (4 partial slices)
    u16* Wc1T  = (u16*)(ws + off); off += (size_t)DH1 * KP2 * 2;     //  4.3 MB
    u16* W2aTs = (u16*)(ws + off); off += (size_t)DH1 * KP2 * 2;
    u16* Wc2T  = (u16*)(ws + off); off += (size_t)DH2 * DH1 * 2;
    u16* W2bTs = (u16*)(ws + off); off += (size_t)DH2 * DH1 * 2;
    u16* Shb   = (u16*)(ws + off); off += (size_t)256 * DH1 * 2;
    // contiguous zero region (cleared by prep_all)
    char* zBase = ws + off;
    float* hacc  = (float*)(ws + off); off += (size_t)6000 * DH1 * 4;  // 12.3 MB
    float* hacc2 = (float*)(ws + off); off += (size_t)6000 * DH2 * 4;  //  6.1 MB
    float* u     = (float*)(ws + off); off += (size_t)256 * DH1 * 4;
    float* u2    = (float*)(ws + off); off += (size_t)256 * DH2 * 4;
    size_t zeroQuads = (size_t)(ws + off - zBase) / 16;
    // aliases: hb reuses XbT (dead after gemmA); g/q/k/v reuse SbT (dead after gemmA)
    u16* hb = XbT;
    float* g = (float*)SbT;
    float* q = g + BT * DH2;
    float* k = q + BT * DH2;
    float* v = k + BT * DH2;

    prep_all<<<NBIGW + NSMALL + NCONV + NZERO, 256, 0, stream>>>(
        W1a, W2a, W1b, W2b, feat, depth,
        Wc1T, W2aTs, Wc2T, W2bTs, XbT, SbT, (float*)zBase, zeroQuads);
    // hacc += XbT@Wc1T (564 blocks, z=3) ; u += SbT@W2aTs (96 blocks, 4 slices folded)
    gemmA<<<564 + 96, 256, 0, stream>>>(XbT, Wc1T, SbT, W2aTs, hacc, u);
    reduce1<<<dim3(BT, 4), 256, 0, stream>>>(hacc, u, b1a, hb, Shb);
    // hacc2 += hb@Wc2T (752 blocks, z=4) ; u2 += Shb@W2bTs (32 blocks, z=4)
    gemmB<<<752 + 32, 256, 0, stream>>>(hb, Wc2T, Shb, W2bTs, hacc2, u2);
    reduce2_qkv<<<BT, DH2, 0, stream>>>(hacc2, u2, b1b, Wq, Wk, Wv, g, q, k, v);
    attn_head<<<BT, DH2, 0, stream>>>(q, k, v, g, Wo, ln1g, ln1b, Wf1, bf1,
                                      Wf2, bf2, ln2g, ln2b, Wc, bc, out);
}